// Round 14
// baseline (2017.911 us; speedup 1.0000x reference)
//
#include <hip/hip_runtime.h>
#include <hip/hip_bf16.h>

// Sizes (fixed by the reference)
#define B_  64
#define C_  16
#define N_  4096
#define T_  12
#define ROWS_ (B_ * T_ * C_)   // 12288
#define NT_ 64                 // bf16 K-tiles of 64 (K = 4096)

typedef __attribute__((ext_vector_type(4))) float f32x4;
typedef __attribute__((ext_vector_type(8))) short s16x8;
typedef __attribute__((ext_vector_type(4))) short s16x4;
typedef __attribute__((ext_vector_type(8))) int   i32x8;
typedef __attribute__((ext_vector_type(4))) int   i32x4;

__device__ __forceinline__ ushort f2bf(float f) {
    unsigned u = __builtin_bit_cast(unsigned, f);
    u += 0x7fffu + ((u >> 16) & 1u);
    return (ushort)(u >> 16);
}
__device__ __forceinline__ float bf2f(ushort v) {
    return __builtin_bit_cast(float, (unsigned)v << 16);
}

// f32 -> OCP e4m3fn with RNE + saturation (inputs finite)
__device__ __forceinline__ uchar f2fp8(float f) {
    float a = fabsf(f);
    unsigned s = (__builtin_bit_cast(unsigned, f) >> 24) & 0x80u;
    if (a >= 448.f) return (uchar)(s | 0x7E);
    if (a < 0.015625f) {                       // subnormal: quantum 2^-9
        int m = (int)rintf(a * 512.f);         // 0..8 (8 encodes 2^-6 correctly)
        return (uchar)(s | (unsigned)m);
    }
    unsigned u = __builtin_bit_cast(unsigned, a);
    unsigned r = (u + 0x7FFFFu + ((u >> 20) & 1u)) >> 20;   // RNE to 3-bit mantissa
    return (uchar)(s | (r - 960u));            // rebias: (exp-120)<<3 | mant
}

// 16x16x16 bf16 MFMA (A 2 VGPRs, B 2 VGPRs, C/D 4) — builtin name varies; asm fallback.
__device__ __forceinline__ f32x4 mfma16x16x16bf16(s16x4 a, s16x4 b, f32x4 c) {
#if __has_builtin(__builtin_amdgcn_mfma_f32_16x16x16_bf16)
    return __builtin_amdgcn_mfma_f32_16x16x16_bf16(a, b, c, 0, 0, 0);
#elif __has_builtin(__builtin_amdgcn_mfma_f32_16x16x16bf16_1k)
    return __builtin_amdgcn_mfma_f32_16x16x16bf16_1k(a, b, c, 0, 0, 0);
#else
    f32x4 d = c;
    asm volatile("v_mfma_f32_16x16x16_bf16 %0, %1, %2, %0"
                 : "+v"(d) : "v"(a), "v"(b));
    return d;
#endif
}

typedef const __attribute__((address_space(1))) unsigned int* gas_t;
typedef __attribute__((address_space(3))) unsigned int* las_t;
__device__ __forceinline__ void gload16(const ushort* g, ushort* l) {
    __builtin_amdgcn_global_load_lds((gas_t)(const void*)g, (las_t)(void*)l, 16, 0, 0);
}
__device__ __forceinline__ void gload16b(const uchar* g, uchar* l) {
    __builtin_amdgcn_global_load_lds((gas_t)(const void*)g, (las_t)(void*)l, 16, 0, 0);
}

// ---------------------------------------------------------------------------
// pack_x: x (B,C,N,T) f32 -> X2 bf16 + X8 fp8 [(b*T+t)*C+c][n]  (row (b,t,c))
// grid (N/32, B), block 256
__global__ __launch_bounds__(256)
void pack_x(const float* __restrict__ x, ushort* __restrict__ X2,
            uchar* __restrict__ X8) {
    __shared__ float xs[16][32][13];
    const int t  = threadIdx.x;
    const int n0 = blockIdx.x * 32;
    const int b  = blockIdx.y;
    #pragma unroll
    for (int p0 = 0; p0 < 2; ++p0) {
        int p = p0 * 256 + t;
        int c = p >> 5, nn = p & 31;
        const float* src = x + (size_t)((b * 16 + c) * 4096 + n0 + nn) * 12;
        float tmp[12];
        *(float4*)(tmp)     = *(const float4*)(src);
        *(float4*)(tmp + 4) = *(const float4*)(src + 4);
        *(float4*)(tmp + 8) = *(const float4*)(src + 8);
        #pragma unroll
        for (int k = 0; k < 12; ++k) xs[c][nn][k] = tmp[k];
    }
    __syncthreads();
    #pragma unroll
    for (int i = 0; i < 24; ++i) {
        int e = i * 256 + t;
        int nn = e & 31, rowi = e >> 5;
        int tt = rowi >> 4, c = rowi & 15;
        float xv = xs[c][nn][tt];
        size_t row = (size_t)(b * 12 + tt) * 16 + c;
        X2[row * 4096 + n0 + nn] = f2bf(xv);
        X8[row * 4096 + n0 + nn] = f2fp8(xv);
    }
}

// ---------------------------------------------------------------------------
// transpose_fp8: S f32 [n][m] -> D fp8 [m][n] scaled by `scale`
// grid (N/64, N/64), block 256
__global__ __launch_bounds__(256)
void transpose_fp8(const float* __restrict__ S, uchar* __restrict__ D, float scale) {
    __shared__ float ld[64][65];
    const int t  = threadIdx.x;
    const int m0 = blockIdx.x * 64;
    const int n0 = blockIdx.y * 64;
    #pragma unroll
    for (int it = 0; it < 4; ++it) {
        int row = it * 16 + (t >> 4);
        int col = (t & 15) * 4;
        float4 v = *(const float4*)&S[(size_t)(n0 + row) * 4096 + m0 + col];
        ld[row][col] = v.x; ld[row][col + 1] = v.y;
        ld[row][col + 2] = v.z; ld[row][col + 3] = v.w;
    }
    __syncthreads();
    #pragma unroll
    for (int it = 0; it < 8; ++it) {
        int mr = it * 8 + (t >> 5);
        int nc = (t & 31) * 2;
        ushort p = (ushort)f2fp8(ld[nc][mr] * scale) |
                   ((ushort)f2fp8(ld[nc + 1][mr] * scale) << 8);
        *(ushort*)&D[(size_t)(m0 + mr) * 4096 + n0 + nc] = p;
    }
}

// ---------------------------------------------------------------------------
// adp_rows: per row n, reduce relu(e1[n,:]·e2[:,m]) over m -> rowmax, rowsum(exp)
__global__ __launch_bounds__(256)
void adp_rows(const float* __restrict__ e1, const float* __restrict__ e2,
              float* __restrict__ maxn, float* __restrict__ sumn) {
    const int n = blockIdx.x, t = threadIdx.x;
    __shared__ float se1[10];
    __shared__ float red[8];
    if (t < 10) se1[t] = e1[n * 10 + t];
    __syncthreads();
    float v[16];
    float mx = -1e30f;
    #pragma unroll
    for (int i = 0; i < 16; ++i) {
        int m = i * 256 + t;
        float s = 0.f;
        #pragma unroll
        for (int k = 0; k < 10; ++k) s += se1[k] * e2[k * 4096 + m];
        s = fmaxf(s, 0.f);
        v[i] = s;
        mx = fmaxf(mx, s);
    }
    for (int o = 32; o; o >>= 1) mx = fmaxf(mx, __shfl_down(mx, o));
    if ((t & 63) == 0) red[t >> 6] = mx;
    __syncthreads();
    if (t == 0) red[4] = fmaxf(fmaxf(red[0], red[1]), fmaxf(red[2], red[3]));
    __syncthreads();
    mx = red[4];
    float sm = 0.f;
    #pragma unroll
    for (int i = 0; i < 16; ++i) sm += __expf(v[i] - mx);
    for (int o = 32; o; o >>= 1) sm += __shfl_down(sm, o);
    __syncthreads();
    if ((t & 63) == 0) red[t >> 6] = sm;
    __syncthreads();
    if (t == 0) { maxn[n] = mx; sumn[n] = red[0] + red[1] + red[2] + red[3]; }
}

// adp_make: D bf16 [m][n] = exp(relu(e1[n]·e2[:,m]) - maxn[n]) / sumn[n]
// grid (N/64, N/64), block 256
__global__ __launch_bounds__(256)
void adp_make(const float* __restrict__ e1, const float* __restrict__ e2,
              const float* __restrict__ maxn, const float* __restrict__ sumn,
              ushort* __restrict__ D) {
    __shared__ float se1[64][10];    // e1 rows n0..n0+63
    __shared__ float se2[10][64];    // e2 cols m0..m0+63
    const int t  = threadIdx.x;
    const int m0 = blockIdx.x * 64;
    const int n0 = blockIdx.y * 64;
    for (int i = t; i < 640; i += 256) ((float*)se1)[i] = e1[n0 * 10 + i];
    for (int i = t; i < 640; i += 256) {
        int k = i >> 6, m = i & 63;
        se2[k][m] = e2[k * 4096 + m0 + m];
    }
    __syncthreads();
    #pragma unroll
    for (int it = 0; it < 8; ++it) {
        int mr = it * 8 + (t >> 5);
        int nc = (t & 31) * 2;
        float v0 = 0.f, v1 = 0.f;
        #pragma unroll
        for (int k = 0; k < 10; ++k) {
            float e2v = se2[k][mr];
            v0 += se1[nc][k] * e2v;
            v1 += se1[nc + 1][k] * e2v;
        }
        v0 = fmaxf(v0, 0.f);
        v1 = fmaxf(v1, 0.f);
        float va = __expf(v0 - maxn[n0 + nc])     / sumn[n0 + nc];
        float vb = __expf(v1 - maxn[n0 + nc + 1]) / sumn[n0 + nc + 1];
        unsigned pack = (unsigned)f2bf(va) | ((unsigned)f2bf(vb) << 16);
        *(unsigned*)&D[(size_t)(m0 + mr) * 4096 + n0 + nc] = pack;
    }
}

// ---------------------------------------------------------------------------
// racc (bf16) RMW/store helper: racc holds ONLY the sum of mix contributions.
__device__ __forceinline__ void racc_update(ushort* __restrict__ racc,
                                            size_t row, size_t col,
                                            const f32x4& d, int initR) {
    if (initR) {
        #pragma unroll
        for (int r = 0; r < 4; ++r)
            racc[(row + r) * 4096 + col] = f2bf(d[r]);
    } else {
        #pragma unroll
        for (int r = 0; r < 4; ++r) {
            ushort* p = &racc[(row + r) * 4096 + col];
            *p = f2bf(bf2f(*p) + d[r]);
        }
    }
}

// ---------------------------------------------------------------------------
// gemm_mix (bf16, adp chain): 256x256 tile, BK=64, 8-phase counted-vmcnt;
// epilogue: optional Y bf16 store + MFMA channel-mix into bf16 racc.
__global__ __launch_bounds__(512, 2)
void gemm_mix(const ushort* __restrict__ Xp, const ushort* __restrict__ Bt,
              ushort* __restrict__ Yp, ushort* __restrict__ racc,
              const float* __restrict__ W, int cblk, int writeY, int initR) {
    __shared__ ushort lds[65536];
    const int tid  = threadIdx.x;
    const int lane = tid & 63;
    const int wid  = tid >> 6;
    const int wm   = wid >> 2;
    const int wn   = wid & 3;
    const int lr   = lane & 15;
    const int lq   = lane >> 4;
    const int fsw  = (lane & 7) << 3;

    int flat = blockIdx.y * gridDim.x + blockIdx.x;
    int swz  = (flat & 7) * 96 + (flat >> 3);
    const size_t r0 = (size_t)(swz >> 4) * 256;
    const size_t c0 = (size_t)(swz & 15) * 256;

#define AIDX(b, mi, ks) (((b) * 32768)          + (((((mi) * 32 + wm * 16 + lr) * 64) + (ks) * 32 + lq * 8) ^ fsw))
#define BIDX(b, nj, ks) (((b) * 32768 + 16384)  + ((((wn * 64 + (nj) * 16 + lr) * 64) + (ks) * 32 + lq * 8) ^ fsw))

#define STAGE(P, rg0, tt, h, mat)                                                      \
    {                                                                                  \
        ushort* _base = &lds[((tt) & 1) * 32768 + (mat) * 16384 + (h) * 8192];         \
        const size_t _k0 = (size_t)(tt) * 64;                                          \
        _Pragma("unroll")                                                              \
        for (int _i = 0; _i < 2; ++_i) {                                               \
            int _e   = (_i * 512 + tid) * 8;                                           \
            int _row = _e >> 6;                                                        \
            int _col = (_e & 63) ^ ((_row & 7) << 3);                                  \
            gload16(&(P)[((rg0) + (h) * 128 + _row) * 4096 + _k0 + _col], &_base[_e]); \
        }                                                                              \
    }

#define PHASE(MI0, STAGE_STMT)                                                                                 \
    {                                                                                                          \
        STAGE_STMT;                                                                                            \
        s16x8 a0 = *(const s16x8*)&lds[AIDX(b, (MI0),     0)];                                                 \
        s16x8 a1 = *(const s16x8*)&lds[AIDX(b, (MI0),     1)];                                                 \
        s16x8 a2 = *(const s16x8*)&lds[AIDX(b, (MI0) + 1, 0)];                                                 \
        s16x8 a3 = *(const s16x8*)&lds[AIDX(b, (MI0) + 1, 1)];                                                 \
        __builtin_amdgcn_s_barrier();                                                                          \
        __builtin_amdgcn_s_setprio(1);                                                                         \
        _Pragma("unroll")                                                                                      \
        for (int nj = 0; nj < 4; ++nj) {                                                                       \
            acc[(MI0)][nj]     = __builtin_amdgcn_mfma_f32_16x16x32_bf16(a0, bfr[nj][0], acc[(MI0)][nj], 0, 0, 0);     \
            acc[(MI0)][nj]     = __builtin_amdgcn_mfma_f32_16x16x32_bf16(a1, bfr[nj][1], acc[(MI0)][nj], 0, 0, 0);     \
            acc[(MI0) + 1][nj] = __builtin_amdgcn_mfma_f32_16x16x32_bf16(a2, bfr[nj][0], acc[(MI0) + 1][nj], 0, 0, 0); \
            acc[(MI0) + 1][nj] = __builtin_amdgcn_mfma_f32_16x16x32_bf16(a3, bfr[nj][1], acc[(MI0) + 1][nj], 0, 0, 0); \
        }                                                                                                      \
        __builtin_amdgcn_s_setprio(0);                                                                         \
    }

    f32x4 acc[8][4] = {};

    STAGE(Xp, r0, 0, 0, 0);
    STAGE(Xp, r0, 0, 1, 0);
    STAGE(Bt, c0, 0, 0, 1);
    STAGE(Bt, c0, 0, 1, 1);
    STAGE(Xp, r0, 1, 0, 0);
    STAGE(Bt, c0, 1, 0, 1);
    asm volatile("s_waitcnt vmcnt(4)" ::: "memory");
    __builtin_amdgcn_s_barrier();

    for (int t = 0; t < NT_; ++t) {
        const int b = t & 1;
        s16x8 bfr[4][2];
        if (t + 1 < NT_) STAGE(Xp, r0, t + 1, 1, 0);
        #pragma unroll
        for (int nj = 0; nj < 4; ++nj) {
            bfr[nj][0] = *(const s16x8*)&lds[BIDX(b, nj, 0)];
            bfr[nj][1] = *(const s16x8*)&lds[BIDX(b, nj, 1)];
        }
        PHASE(0, {});
        __builtin_amdgcn_s_barrier();
        PHASE(2, { if (t + 1 < NT_) STAGE(Bt, c0, t + 1, 1, 1); });
        __builtin_amdgcn_s_barrier();
        PHASE(4, { if (t + 2 < NT_) STAGE(Xp, r0, t + 2, 0, 0); });
        __builtin_amdgcn_s_barrier();
        PHASE(6, { if (t + 2 < NT_) STAGE(Bt, c0, t + 2, 0, 1); });
        if (t < NT_ - 2)       { asm volatile("s_waitcnt vmcnt(4)" ::: "memory"); }
        else if (t == NT_ - 2) { asm volatile("s_waitcnt vmcnt(0)" ::: "memory"); }
        __builtin_amdgcn_sched_barrier(0);
        __builtin_amdgcn_s_barrier();
    }

    if (writeY) {
        #pragma unroll
        for (int mi = 0; mi < 8; ++mi) {
            #pragma unroll
            for (int nj = 0; nj < 4; ++nj) {
                const int col = wn * 64 + nj * 16 + lr;
                #pragma unroll
                for (int r = 0; r < 4; ++r) {
                    const int rr = mi * 32 + wm * 16 + lq * 4 + r;
                    lds[(rr * 256 + col) ^ ((rr & 7) << 3)] = f2bf(acc[mi][nj][r]);
                }
            }
        }
        __syncthreads();
        #pragma unroll
        for (int it = 0; it < 16; ++it) {
            int e = it * 4096 + tid * 8;
            int row = e >> 8, colu = e & 255;
            s16x8 v = *(const s16x8*)&lds[e ^ ((row & 7) << 3)];
            *(s16x8*)&Yp[(r0 + row) * 4096 + c0 + colu] = v;
        }
    }

    // MFMA channel-mix into bf16 racc (scattered per-lane RMW)
    {
        const float4 wv4 = *(const float4*)&W[(size_t)lr * 112 + cblk + lq * 4];
        s16x4 wf;
        wf[0] = (short)f2bf(wv4.x); wf[1] = (short)f2bf(wv4.y);
        wf[2] = (short)f2bf(wv4.z); wf[3] = (short)f2bf(wv4.w);
        #pragma unroll
        for (int mi = 0; mi < 8; ++mi) {
            #pragma unroll
            for (int nj = 0; nj < 4; ++nj) {
                s16x4 cb;
                cb[0] = (short)f2bf(acc[mi][nj][0]); cb[1] = (short)f2bf(acc[mi][nj][1]);
                cb[2] = (short)f2bf(acc[mi][nj][2]); cb[3] = (short)f2bf(acc[mi][nj][3]);
                f32x4 d = mfma16x16x16bf16(wf, cb, (f32x4){0.f, 0.f, 0.f, 0.f});
                racc_update(racc, r0 + (size_t)mi * 32 + wm * 16 + lq * 4,
                            c0 + wn * 64 + nj * 16 + lr, d, initR);
            }
        }
    }
#undef AIDX
#undef BIDX
#undef STAGE
#undef PHASE
}

// ---------------------------------------------------------------------------
// gemm_fp8: MX-fp8 GEMM (256x256 tile, BK=128, 32 K-tiles, 2 phases/tile).
//   acc = TRUE values (HW scale-fold). Epilogue: optional Y fp8 store (*ysc)
//   + MFMA channel-mix into bf16 racc (scattered per-lane RMW).
__device__ __forceinline__ i32x8 ldfrag8(const uchar* lds8, int rbase, int row, int lq) {
    const int sw = (row & 7) << 4;
    const int b  = rbase + row * 128;
    i32x4 lo = *(const i32x4*)&lds8[b + ((lq * 32) ^ sw)];
    i32x4 hi = *(const i32x4*)&lds8[b + ((lq * 32 + 16) ^ sw)];
    return (i32x8){lo[0], lo[1], lo[2], lo[3], hi[0], hi[1], hi[2], hi[3]};
}

__global__ __launch_bounds__(512, 2)
void gemm_fp8(const uchar* __restrict__ Xp, const uchar* __restrict__ Bt,
              uchar* __restrict__ Yp, ushort* __restrict__ racc,
              const float* __restrict__ W, int cblk, int writeY, int initR,
              int sA, int sB, float ysc) {
    __shared__ uchar lds8[131072];   // 2 buf x (A 32KB + B 32KB)
    const int tid  = threadIdx.x;
    const int lane = tid & 63;
    const int wid  = tid >> 6;
    const int wm   = wid >> 2;
    const int wn   = wid & 3;
    const int lr   = lane & 15;
    const int lq   = lane >> 4;

    int flat = blockIdx.y * gridDim.x + blockIdx.x;   // grid (16,48)
    int swz  = (flat & 7) * 96 + (flat >> 3);
    const size_t r0 = (size_t)(swz >> 4) * 256;
    const size_t c0 = (size_t)(swz & 15) * 256;

#define STAGE8(P, rg0, tt, h, mat)                                                       \
    {                                                                                    \
        uchar* _base = &lds8[((tt) & 1) * 65536 + (mat) * 32768 + (h) * 16384];          \
        const size_t _k0 = (size_t)(tt) * 128;                                           \
        _Pragma("unroll")                                                                \
        for (int _i = 0; _i < 2; ++_i) {                                                 \
            int _e   = (_i * 512 + tid) * 16;                                            \
            int _row = _e >> 7;                                                          \
            int _col = (_e & 127) ^ ((_row & 7) << 4);                                   \
            gload16b(&(P)[((rg0) + (h) * 128 + _row) * 4096 + _k0 + _col], &_base[_e]);  \
        }                                                                                \
    }

    f32x4 acc[8][4] = {};

    STAGE8(Xp, r0, 0, 0, 0);
    STAGE8(Xp, r0, 0, 1, 0);
    STAGE8(Bt, c0, 0, 0, 1);
    STAGE8(Bt, c0, 0, 1, 1);
    STAGE8(Xp, r0, 1, 0, 0);
    STAGE8(Bt, c0, 1, 0, 1);
    asm volatile("s_waitcnt vmcnt(4)" ::: "memory");
    __builtin_amdgcn_s_barrier();

    for (int t = 0; t < 32; ++t) {
        const int bb = (t & 1) * 65536;
        i32x8 bf[4];
        // ===== phase 0: stage A1(t+1), B1(t+1); compute mi 0-3 =====
        if (t + 1 < 32) STAGE8(Xp, r0, t + 1, 1, 0);
        #pragma unroll
        for (int nj = 0; nj < 4; ++nj)
            bf[nj] = ldfrag8(lds8, bb + 32768, wn * 64 + nj * 16 + lr, lq);
        i32x8 af0 = ldfrag8(lds8, bb,       wm * 16 + lr, lq);
        i32x8 af1 = ldfrag8(lds8, bb,  32 + wm * 16 + lr, lq);
        i32x8 af2 = ldfrag8(lds8, bb,  64 + wm * 16 + lr, lq);
        i32x8 af3 = ldfrag8(lds8, bb,  96 + wm * 16 + lr, lq);
        if (t + 1 < 32) STAGE8(Bt, c0, t + 1, 1, 1);
        __builtin_amdgcn_s_barrier();
        __builtin_amdgcn_s_setprio(1);
        #pragma unroll
        for (int nj = 0; nj < 4; ++nj) {
            acc[0][nj] = __builtin_amdgcn_mfma_scale_f32_16x16x128_f8f6f4(af0, bf[nj], acc[0][nj], 0, 0, 0, sA, 0, sB);
            acc[1][nj] = __builtin_amdgcn_mfma_scale_f32_16x16x128_f8f6f4(af1, bf[nj], acc[1][nj], 0, 0, 0, sA, 0, sB);
            acc[2][nj] = __builtin_amdgcn_mfma_scale_f32_16x16x128_f8f6f4(af2, bf[nj], acc[2][nj], 0, 0, 0, sA, 0, sB);
            acc[3][nj] = __builtin_amdgcn_mfma_scale_f32_16x16x128_f8f6f4(af3, bf[nj], acc[3][nj], 0, 0, 0, sA, 0, sB);
        }
        __builtin_amdgcn_s_setprio(0);
        __builtin_amdgcn_s_barrier();
        // ===== phase 1: stage A0(t+2), B0(t+2); compute mi 4-7 =====
        if (t + 2 < 32) STAGE8(Xp, r0, t + 2, 0, 0);
        af0 = ldfrag8(lds8, bb, 128 + wm * 16 + lr, lq);
        af1 = ldfrag8(lds8, bb, 160 + wm * 16 + lr, lq);
        af2 = ldfrag8(lds8, bb, 192 + wm * 16 + lr, lq);
        af3 = ldfrag8(lds8, bb, 224 + wm * 16 + lr, lq);
        if (t + 2 < 32) STAGE8(Bt, c0, t + 2, 0, 1);
        __builtin_amdgcn_s_barrier();
        __builtin_amdgcn_s_setprio(1);
        #pragma unroll
        for (int nj = 0; nj < 4; ++nj) {
            acc[4][nj] = __builtin_amdgcn_mfma_scale_f32_16x16x128_f8f6f4(af0, bf[nj], acc[4][nj], 0, 0, 0, sA, 0, sB);
            acc[5][nj] = __builtin_amdgcn_mfma_scale_f32_16x16x128_f8f6f4(af1, bf[nj], acc[5][nj], 0, 0, 0, sA, 0, sB);
            acc[6][nj] = __builtin_amdgcn_mfma_scale_f32_16x16x128_f8f6f4(af2, bf[nj], acc[6][nj], 0, 0, 0, sA, 0, sB);
            acc[7][nj] = __builtin_amdgcn_mfma_scale_f32_16x16x128_f8f6f4(af3, bf[nj], acc[7][nj], 0, 0, 0, sA, 0, sB);
        }
        __builtin_amdgcn_s_setprio(0);
        if (t < 30)       { asm volatile("s_waitcnt vmcnt(4)" ::: "memory"); }
        else if (t == 30) { asm volatile("s_waitcnt vmcnt(0)" ::: "memory"); }
        __builtin_amdgcn_sched_barrier(0);
        __builtin_amdgcn_s_barrier();
    }

    // epilogue 1: Y fp8 store (value * ysc), LDS restage for coalescing
    if (writeY) {
        #pragma unroll
        for (int mi = 0; mi < 8; ++mi) {
            #pragma unroll
            for (int nj = 0; nj < 4; ++nj) {
                const int col = wn * 64 + nj * 16 + lr;
                #pragma unroll
                for (int r = 0; r < 4; ++r) {
                    const int rr = mi * 32 + wm * 16 + lq * 4 + r;
                    lds8[(rr * 256 + col) ^ ((rr & 7) << 4)] = f2fp8(acc[mi][nj][r] * ysc);
                }
            }
        }
        __syncthreads();
        #pragma unroll
        for (int it = 0; it < 8; ++it) {
            int e = it * 8192 + tid * 16;
            int row = e >> 8, colu = e & 255;
            i32x4 v = *(const i32x4*)&lds8[e ^ ((row & 7) << 4)];
            *(i32x4*)&Yp[(r0 + row) * 4096 + c0 + colu] = v;
        }
    }

    // epilogue 2: MFMA channel-mix into bf16 racc (scattered per-lane RMW)
    {
        const float4 wv4 = *(const float4*)&W[(size_t)lr * 112 + cblk + lq * 4];
        s16x4 wf;
        wf[0] = (short)f2bf(wv4.x); wf[1] = (short)f2bf(wv4.y);
        wf[2] = (short)f2bf(wv4.z); wf[3] = (short)f2bf(wv4.w);
        #pragma unroll
        for (int mi = 0; mi < 8; ++mi) {
            #pragma unroll
            for (int nj = 0; nj < 4; ++nj) {
                s16x4 cb;
                cb[0] = (short)f2bf(acc[mi][nj][0]); cb[1] = (short)f2bf(acc[mi][nj][1]);
                cb[2] = (short)f2bf(acc[mi][nj][2]); cb[3] = (short)f2bf(acc[mi][nj][3]);
                f32x4 d = mfma16x16x16bf16(wf, cb, (f32x4){0.f, 0.f, 0.f, 0.f});
                racc_update(racc, r0 + (size_t)mi * 32 + wm * 16 + lq * 4,
                            c0 + wn * 64 + nj * 16 + lr, d, initR);
            }
        }
    }
#undef STAGE8
}

// ---------------------------------------------------------------------------
// final_out: out[b,c,n,t] = x + bias[c] + W0-mix(x) + racc[(b*12+t)*16+c][n]
// x taken from X2 (bf16). grid (N/32, B), block 256
__global__ __launch_bounds__(256)
void final_out(const ushort* __restrict__ racc, const ushort* __restrict__ X2,
               const float* __restrict__ W, const float* __restrict__ bias,
               float* __restrict__ out) {
    __shared__ float fr[192][32];
    __shared__ float xsb[192][32];
    __shared__ float sW[16][16];
    __shared__ float sb[16];
    const int t  = threadIdx.x;
    const int n0 = blockIdx.x * 32;
    const int b  = blockIdx.y;
    sW[t >> 4][t & 15] = W[(t >> 4) * 112 + (t & 15)];
    if (t < 16) sb[t] = bias[t];
    #pragma unroll
    for (int i = 0; i < 24; ++i) {
        int e = i * 256 + t;
        int rr = e >> 5, nn = e & 31;
        size_t off = ((size_t)b * 192 + rr) * 4096 + n0 + nn;
        fr[rr][nn]  = bf2f(racc[off]);
        xsb[rr][nn] = bf2f(X2[off]);
    }
    __syncthreads();
    #pragma unroll
    for (int p0 = 0; p0 < 2; ++p0) {
        int p = p0 * 256 + t;
        int c = p >> 5, nn = p & 31;
        float buf[12];
        #pragma unroll
        for (int tt = 0; tt < 12; ++tt) {
            float acc = xsb[tt * 16 + c][nn] + sb[c] + fr[tt * 16 + c][nn];
            #pragma unroll
            for (int cp = 0; cp < 16; ++cp) acc += sW[c][cp] * xsb[tt * 16 + cp][nn];
            buf[tt] = acc;
        }
        float* dst = &out[(size_t)((b * 16 + c) * 4096 + n0 + nn) * 12];
        *(float4*)(dst)     = *(float4*)(buf);
        *(float4*)(dst + 4) = *(float4*)(buf + 4);
        *(float4*)(dst + 8) = *(float4*)(buf + 8);
    }
}

// ---------------------------------------------------------------------------
extern "C" void kernel_launch(void* const* d_in, const int* in_sizes, int n_in,
                              void* d_out, int out_size, void* d_ws, size_t ws_size,
                              hipStream_t stream) {
    const float* x    = (const float*)d_in[0];
    const float* s0   = (const float*)d_in[1];
    const float* s1   = (const float*)d_in[2];
    const float* e1   = (const float*)d_in[3];
    const float* e2   = (const float*)d_in[4];
    const float* W    = (const float*)d_in[5];
    const float* bias = (const float*)d_in[6];
    float* out = (float*)d_out;

    // Workspace layout (~403 MB):
    //  X2 bf16 100.66 | racc bf16 100.66 | REGA 100.66 (Y80+Y81 fp8 -> Y1adp bf16)
    //  | X8 fp8 50.33 | SF fp8 16.78 | ADT bf16 33.55 | maxn/sumn 32KB
    char* ws = (char*)d_ws;
    const size_t SZ_X2 = (size_t)ROWS_ * 4096 * 2;
    const size_t SZ_X8 = (size_t)ROWS_ * 4096;
    const size_t SZ_SF = (size_t)4096 * 4096;

    ushort* X2   = (ushort*)(ws);
    ushort* racc = (ushort*)(ws + SZ_X2);
    char*   REGA = ws + 2 * SZ_X2;
    uchar*  X8   = (uchar*)(REGA + SZ_X2);
    uchar*  SF   = (uchar*)((char*)X8 + SZ_X8);
    ushort* ADT  = (ushort*)((char*)SF + SZ_SF);
    float*  maxn = (float*)((char*)ADT + SZ_SF * 2);
    float*  sumn = maxn + 4096;

    uchar*  Y80   = (uchar*)REGA;              // s0 chain Y1 (fp8 * 2^6)
    uchar*  Y81   = (uchar*)REGA + SZ_X8;      // s1 chain Y1
    ushort* Y1adp = (ushort*)REGA;             // adp chain Y1 (bf16), after Y8 dead

    const int S_ONE = 0x7F7F7F7F;   // E8M0 2^0
    const int S_M6  = 0x79797979;   // 2^-6  (s-chain Y stored *2^6)
    const int S_M12 = 0x73737373;   // 2^-12 (supports stored *2^12)

    pack_x<<<dim3(128, 64), 256, 0, stream>>>(x, X2, X8);
    transpose_fp8<<<dim3(64, 64), 256, 0, stream>>>(s0, SF, 4096.f);
    adp_rows<<<4096, 256, 0, stream>>>(e1, e2, maxn, sumn);
    adp_make<<<dim3(64, 64), 256, 0, stream>>>(e1, e2, maxn, sumn, ADT);

    // s0 chain (fp8) — first GEMM initializes racc (store, no read)
    gemm_fp8<<<dim3(16, 48), 512, 0, stream>>>(X8,  SF, Y80, racc, W, 16, 1, 1, S_ONE, S_M12, 64.f);
    gemm_fp8<<<dim3(16, 48), 512, 0, stream>>>(Y80, SF, Y80, racc, W, 32, 0, 0, S_M6,  S_M12, 0.f);
    // s1 chain (fp8) — SF reused after s0 chain finished
    transpose_fp8<<<dim3(64, 64), 256, 0, stream>>>(s1, SF, 4096.f);
    gemm_fp8<<<dim3(16, 48), 512, 0, stream>>>(X8,  SF, Y81, racc, W, 48, 1, 0, S_ONE, S_M12, 64.f);
    gemm_fp8<<<dim3(16, 48), 512, 0, stream>>>(Y81, SF, Y81, racc, W, 64, 0, 0, S_M6,  S_M12, 0.f);
    // adp chain (bf16) — Y1adp overwrites dead Y80/Y81
    gemm_mix<<<dim3(16, 48), 512, 0, stream>>>(X2,    ADT, Y1adp, racc, W, 80, 1, 0);
    gemm_mix<<<dim3(16, 48), 512, 0, stream>>>(Y1adp, ADT, Y1adp, racc, W, 96, 0, 0);

    final_out<<<dim3(128, 64), 256, 0, stream>>>(racc, X2, W, bias, out);
}

// Round 15
// 2009.374 us; speedup vs baseline: 1.0042x; 1.0042x over previous
//
#include <hip/hip_runtime.h>
#include <hip/hip_bf16.h>

// Sizes (fixed by the reference)
#define B_  64
#define C_  16
#define N_  4096
#define T_  12
#define ROWS_ (B_ * T_ * C_)   // 12288
#define NT_ 64                 // bf16 K-tiles of 64 (K = 4096)

typedef __attribute__((ext_vector_type(4))) float f32x4;
typedef __attribute__((ext_vector_type(8))) short s16x8;
typedef __attribute__((ext_vector_type(4))) short s16x4;
typedef __attribute__((ext_vector_type(8))) int   i32x8;
typedef __attribute__((ext_vector_type(4))) int   i32x4;

__device__ __forceinline__ ushort f2bf(float f) {
    unsigned u = __builtin_bit_cast(unsigned, f);
    u += 0x7fffu + ((u >> 16) & 1u);
    return (ushort)(u >> 16);
}
__device__ __forceinline__ float bf2f(ushort v) {
    return __builtin_bit_cast(float, (unsigned)v << 16);
}

// f32 -> OCP e4m3fn with RNE + saturation (inputs finite)
__device__ __forceinline__ uchar f2fp8(float f) {
    float a = fabsf(f);
    unsigned s = (__builtin_bit_cast(unsigned, f) >> 24) & 0x80u;
    if (a >= 448.f) return (uchar)(s | 0x7E);
    if (a < 0.015625f) {                       // subnormal: quantum 2^-9
        int m = (int)rintf(a * 512.f);         // 0..8 (8 encodes 2^-6 correctly)
        return (uchar)(s | (unsigned)m);
    }
    unsigned u = __builtin_bit_cast(unsigned, a);
    unsigned r = (u + 0x7FFFFu + ((u >> 20) & 1u)) >> 20;   // RNE to 3-bit mantissa
    return (uchar)(s | (r - 960u));            // rebias: (exp-120)<<3 | mant
}

// 16x16x16 bf16 MFMA (A 2 VGPRs, B 2 VGPRs, C/D 4) — builtin name varies; asm fallback.
__device__ __forceinline__ f32x4 mfma16x16x16bf16(s16x4 a, s16x4 b, f32x4 c) {
#if __has_builtin(__builtin_amdgcn_mfma_f32_16x16x16_bf16)
    return __builtin_amdgcn_mfma_f32_16x16x16_bf16(a, b, c, 0, 0, 0);
#elif __has_builtin(__builtin_amdgcn_mfma_f32_16x16x16bf16_1k)
    return __builtin_amdgcn_mfma_f32_16x16x16bf16_1k(a, b, c, 0, 0, 0);
#else
    f32x4 d = c;
    asm volatile("v_mfma_f32_16x16x16_bf16 %0, %1, %2, %0"
                 : "+v"(d) : "v"(a), "v"(b));
    return d;
#endif
}

typedef const __attribute__((address_space(1))) unsigned int* gas_t;
typedef __attribute__((address_space(3))) unsigned int* las_t;
__device__ __forceinline__ void gload16(const ushort* g, ushort* l) {
    __builtin_amdgcn_global_load_lds((gas_t)(const void*)g, (las_t)(void*)l, 16, 0, 0);
}
__device__ __forceinline__ void gload16b(const uchar* g, uchar* l) {
    __builtin_amdgcn_global_load_lds((gas_t)(const void*)g, (las_t)(void*)l, 16, 0, 0);
}

// ---------------------------------------------------------------------------
// pack_x: x (B,C,N,T) f32 -> X2 bf16 + X8 fp8 [(b*T+t)*C+c][n]  (row (b,t,c))
// grid (N/32, B), block 256
__global__ __launch_bounds__(256)
void pack_x(const float* __restrict__ x, ushort* __restrict__ X2,
            uchar* __restrict__ X8) {
    __shared__ float xs[16][32][13];
    const int t  = threadIdx.x;
    const int n0 = blockIdx.x * 32;
    const int b  = blockIdx.y;
    #pragma unroll
    for (int p0 = 0; p0 < 2; ++p0) {
        int p = p0 * 256 + t;
        int c = p >> 5, nn = p & 31;
        const float* src = x + (size_t)((b * 16 + c) * 4096 + n0 + nn) * 12;
        float tmp[12];
        *(float4*)(tmp)     = *(const float4*)(src);
        *(float4*)(tmp + 4) = *(const float4*)(src + 4);
        *(float4*)(tmp + 8) = *(const float4*)(src + 8);
        #pragma unroll
        for (int k = 0; k < 12; ++k) xs[c][nn][k] = tmp[k];
    }
    __syncthreads();
    #pragma unroll
    for (int i = 0; i < 24; ++i) {
        int e = i * 256 + t;
        int nn = e & 31, rowi = e >> 5;
        int tt = rowi >> 4, c = rowi & 15;
        float xv = xs[c][nn][tt];
        size_t row = (size_t)(b * 12 + tt) * 16 + c;
        X2[row * 4096 + n0 + nn] = f2bf(xv);
        X8[row * 4096 + n0 + nn] = f2fp8(xv);
    }
}

// ---------------------------------------------------------------------------
// transpose_fp8: S f32 [n][m] -> D fp8 [m][n] scaled by `scale`
// grid (N/64, N/64), block 256
__global__ __launch_bounds__(256)
void transpose_fp8(const float* __restrict__ S, uchar* __restrict__ D, float scale) {
    __shared__ float ld[64][65];
    const int t  = threadIdx.x;
    const int m0 = blockIdx.x * 64;
    const int n0 = blockIdx.y * 64;
    #pragma unroll
    for (int it = 0; it < 4; ++it) {
        int row = it * 16 + (t >> 4);
        int col = (t & 15) * 4;
        float4 v = *(const float4*)&S[(size_t)(n0 + row) * 4096 + m0 + col];
        ld[row][col] = v.x; ld[row][col + 1] = v.y;
        ld[row][col + 2] = v.z; ld[row][col + 3] = v.w;
    }
    __syncthreads();
    #pragma unroll
    for (int it = 0; it < 8; ++it) {
        int mr = it * 8 + (t >> 5);
        int nc = (t & 31) * 2;
        ushort p = (ushort)f2fp8(ld[nc][mr] * scale) |
                   ((ushort)f2fp8(ld[nc + 1][mr] * scale) << 8);
        *(ushort*)&D[(size_t)(m0 + mr) * 4096 + n0 + nc] = p;
    }
}

// ---------------------------------------------------------------------------
// adp_rows: per row n, reduce relu(e1[n,:]·e2[:,m]) over m -> rowmax, rowsum(exp)
__global__ __launch_bounds__(256)
void adp_rows(const float* __restrict__ e1, const float* __restrict__ e2,
              float* __restrict__ maxn, float* __restrict__ sumn) {
    const int n = blockIdx.x, t = threadIdx.x;
    __shared__ float se1[10];
    __shared__ float red[8];
    if (t < 10) se1[t] = e1[n * 10 + t];
    __syncthreads();
    float v[16];
    float mx = -1e30f;
    #pragma unroll
    for (int i = 0; i < 16; ++i) {
        int m = i * 256 + t;
        float s = 0.f;
        #pragma unroll
        for (int k = 0; k < 10; ++k) s += se1[k] * e2[k * 4096 + m];
        s = fmaxf(s, 0.f);
        v[i] = s;
        mx = fmaxf(mx, s);
    }
    for (int o = 32; o; o >>= 1) mx = fmaxf(mx, __shfl_down(mx, o));
    if ((t & 63) == 0) red[t >> 6] = mx;
    __syncthreads();
    if (t == 0) red[4] = fmaxf(fmaxf(red[0], red[1]), fmaxf(red[2], red[3]));
    __syncthreads();
    mx = red[4];
    float sm = 0.f;
    #pragma unroll
    for (int i = 0; i < 16; ++i) sm += __expf(v[i] - mx);
    for (int o = 32; o; o >>= 1) sm += __shfl_down(sm, o);
    __syncthreads();
    if ((t & 63) == 0) red[t >> 6] = sm;
    __syncthreads();
    if (t == 0) { maxn[n] = mx; sumn[n] = red[0] + red[1] + red[2] + red[3]; }
}

// adp_make: D bf16 [m][n] = exp(relu(e1[n]·e2[:,m]) - maxn[n]) / sumn[n]
// grid (N/64, N/64), block 256
__global__ __launch_bounds__(256)
void adp_make(const float* __restrict__ e1, const float* __restrict__ e2,
              const float* __restrict__ maxn, const float* __restrict__ sumn,
              ushort* __restrict__ D) {
    __shared__ float se1[64][10];    // e1 rows n0..n0+63
    __shared__ float se2[10][64];    // e2 cols m0..m0+63
    const int t  = threadIdx.x;
    const int m0 = blockIdx.x * 64;
    const int n0 = blockIdx.y * 64;
    for (int i = t; i < 640; i += 256) ((float*)se1)[i] = e1[n0 * 10 + i];
    for (int i = t; i < 640; i += 256) {
        int k = i >> 6, m = i & 63;
        se2[k][m] = e2[k * 4096 + m0 + m];
    }
    __syncthreads();
    #pragma unroll
    for (int it = 0; it < 8; ++it) {
        int mr = it * 8 + (t >> 5);
        int nc = (t & 31) * 2;
        float v0 = 0.f, v1 = 0.f;
        #pragma unroll
        for (int k = 0; k < 10; ++k) {
            float e2v = se2[k][mr];
            v0 += se1[nc][k] * e2v;
            v1 += se1[nc + 1][k] * e2v;
        }
        v0 = fmaxf(v0, 0.f);
        v1 = fmaxf(v1, 0.f);
        float va = __expf(v0 - maxn[n0 + nc])     / sumn[n0 + nc];
        float vb = __expf(v1 - maxn[n0 + nc + 1]) / sumn[n0 + nc + 1];
        unsigned pack = (unsigned)f2bf(va) | ((unsigned)f2bf(vb) << 16);
        *(unsigned*)&D[(size_t)(m0 + mr) * 4096 + n0 + nc] = pack;
    }
}

// ---------------------------------------------------------------------------
// racc (bf16) RMW/store helper: racc holds ONLY the sum of mix contributions.
__device__ __forceinline__ void racc_update(ushort* __restrict__ racc,
                                            size_t row, size_t col,
                                            const f32x4& d, int initR) {
    if (initR) {
        #pragma unroll
        for (int r = 0; r < 4; ++r)
            racc[(row + r) * 4096 + col] = f2bf(d[r]);
    } else {
        #pragma unroll
        for (int r = 0; r < 4; ++r) {
            ushort* p = &racc[(row + r) * 4096 + col];
            *p = f2bf(bf2f(*p) + d[r]);
        }
    }
}

// ---------------------------------------------------------------------------
// gemm_mix (bf16, adp chain): 256x256 tile, BK=64, 8-phase counted-vmcnt;
// epilogue: optional Y bf16 store + MFMA channel-mix into bf16 racc.
// launch_bounds(512,1): residency is LDS/reg-capped at 1 block anyway;
// relaxing the register cap gives the allocator headroom in the K-loop.
__global__ __launch_bounds__(512, 1)
void gemm_mix(const ushort* __restrict__ Xp, const ushort* __restrict__ Bt,
              ushort* __restrict__ Yp, ushort* __restrict__ racc,
              const float* __restrict__ W, int cblk, int writeY, int initR) {
    __shared__ ushort lds[65536];
    const int tid  = threadIdx.x;
    const int lane = tid & 63;
    const int wid  = tid >> 6;
    const int wm   = wid >> 2;
    const int wn   = wid & 3;
    const int lr   = lane & 15;
    const int lq   = lane >> 4;
    const int fsw  = (lane & 7) << 3;

    int flat = blockIdx.y * gridDim.x + blockIdx.x;
    int swz  = (flat & 7) * 96 + (flat >> 3);
    const size_t r0 = (size_t)(swz >> 4) * 256;
    const size_t c0 = (size_t)(swz & 15) * 256;

#define AIDX(b, mi, ks) (((b) * 32768)          + (((((mi) * 32 + wm * 16 + lr) * 64) + (ks) * 32 + lq * 8) ^ fsw))
#define BIDX(b, nj, ks) (((b) * 32768 + 16384)  + ((((wn * 64 + (nj) * 16 + lr) * 64) + (ks) * 32 + lq * 8) ^ fsw))

#define STAGE(P, rg0, tt, h, mat)                                                      \
    {                                                                                  \
        ushort* _base = &lds[((tt) & 1) * 32768 + (mat) * 16384 + (h) * 8192];         \
        const size_t _k0 = (size_t)(tt) * 64;                                          \
        _Pragma("unroll")                                                              \
        for (int _i = 0; _i < 2; ++_i) {                                               \
            int _e   = (_i * 512 + tid) * 8;                                           \
            int _row = _e >> 6;                                                        \
            int _col = (_e & 63) ^ ((_row & 7) << 3);                                  \
            gload16(&(P)[((rg0) + (h) * 128 + _row) * 4096 + _k0 + _col], &_base[_e]); \
        }                                                                              \
    }

#define PHASE(MI0, STAGE_STMT)                                                                                 \
    {                                                                                                          \
        STAGE_STMT;                                                                                            \
        s16x8 a0 = *(const s16x8*)&lds[AIDX(b, (MI0),     0)];                                                 \
        s16x8 a1 = *(const s16x8*)&lds[AIDX(b, (MI0),     1)];                                                 \
        s16x8 a2 = *(const s16x8*)&lds[AIDX(b, (MI0) + 1, 0)];                                                 \
        s16x8 a3 = *(const s16x8*)&lds[AIDX(b, (MI0) + 1, 1)];                                                 \
        __builtin_amdgcn_s_barrier();                                                                          \
        __builtin_amdgcn_s_setprio(1);                                                                         \
        _Pragma("unroll")                                                                                      \
        for (int nj = 0; nj < 4; ++nj) {                                                                       \
            acc[(MI0)][nj]     = __builtin_amdgcn_mfma_f32_16x16x32_bf16(a0, bfr[nj][0], acc[(MI0)][nj], 0, 0, 0);     \
            acc[(MI0)][nj]     = __builtin_amdgcn_mfma_f32_16x16x32_bf16(a1, bfr[nj][1], acc[(MI0)][nj], 0, 0, 0);     \
            acc[(MI0) + 1][nj] = __builtin_amdgcn_mfma_f32_16x16x32_bf16(a2, bfr[nj][0], acc[(MI0) + 1][nj], 0, 0, 0); \
            acc[(MI0) + 1][nj] = __builtin_amdgcn_mfma_f32_16x16x32_bf16(a3, bfr[nj][1], acc[(MI0) + 1][nj], 0, 0, 0); \
        }                                                                                                      \
        __builtin_amdgcn_s_setprio(0);                                                                         \
    }

    f32x4 acc[8][4] = {};

    STAGE(Xp, r0, 0, 0, 0);
    STAGE(Xp, r0, 0, 1, 0);
    STAGE(Bt, c0, 0, 0, 1);
    STAGE(Bt, c0, 0, 1, 1);
    STAGE(Xp, r0, 1, 0, 0);
    STAGE(Bt, c0, 1, 0, 1);
    asm volatile("s_waitcnt vmcnt(4)" ::: "memory");
    __builtin_amdgcn_s_barrier();

    for (int t = 0; t < NT_; ++t) {
        const int b = t & 1;
        s16x8 bfr[4][2];
        if (t + 1 < NT_) STAGE(Xp, r0, t + 1, 1, 0);
        #pragma unroll
        for (int nj = 0; nj < 4; ++nj) {
            bfr[nj][0] = *(const s16x8*)&lds[BIDX(b, nj, 0)];
            bfr[nj][1] = *(const s16x8*)&lds[BIDX(b, nj, 1)];
        }
        PHASE(0, {});
        __builtin_amdgcn_s_barrier();
        PHASE(2, { if (t + 1 < NT_) STAGE(Bt, c0, t + 1, 1, 1); });
        __builtin_amdgcn_s_barrier();
        PHASE(4, { if (t + 2 < NT_) STAGE(Xp, r0, t + 2, 0, 0); });
        __builtin_amdgcn_s_barrier();
        PHASE(6, { if (t + 2 < NT_) STAGE(Bt, c0, t + 2, 0, 1); });
        if (t < NT_ - 2)       { asm volatile("s_waitcnt vmcnt(4)" ::: "memory"); }
        else if (t == NT_ - 2) { asm volatile("s_waitcnt vmcnt(0)" ::: "memory"); }
        __builtin_amdgcn_sched_barrier(0);
        __builtin_amdgcn_s_barrier();
    }

    if (writeY) {
        #pragma unroll
        for (int mi = 0; mi < 8; ++mi) {
            #pragma unroll
            for (int nj = 0; nj < 4; ++nj) {
                const int col = wn * 64 + nj * 16 + lr;
                #pragma unroll
                for (int r = 0; r < 4; ++r) {
                    const int rr = mi * 32 + wm * 16 + lq * 4 + r;
                    lds[(rr * 256 + col) ^ ((rr & 7) << 3)] = f2bf(acc[mi][nj][r]);
                }
            }
        }
        __syncthreads();
        #pragma unroll
        for (int it = 0; it < 16; ++it) {
            int e = it * 4096 + tid * 8;
            int row = e >> 8, colu = e & 255;
            s16x8 v = *(const s16x8*)&lds[e ^ ((row & 7) << 3)];
            *(s16x8*)&Yp[(r0 + row) * 4096 + c0 + colu] = v;
        }
    }

    // MFMA channel-mix into bf16 racc (scattered per-lane RMW)
    {
        const float4 wv4 = *(const float4*)&W[(size_t)lr * 112 + cblk + lq * 4];
        s16x4 wf;
        wf[0] = (short)f2bf(wv4.x); wf[1] = (short)f2bf(wv4.y);
        wf[2] = (short)f2bf(wv4.z); wf[3] = (short)f2bf(wv4.w);
        #pragma unroll
        for (int mi = 0; mi < 8; ++mi) {
            #pragma unroll
            for (int nj = 0; nj < 4; ++nj) {
                s16x4 cb;
                cb[0] = (short)f2bf(acc[mi][nj][0]); cb[1] = (short)f2bf(acc[mi][nj][1]);
                cb[2] = (short)f2bf(acc[mi][nj][2]); cb[3] = (short)f2bf(acc[mi][nj][3]);
                f32x4 d = mfma16x16x16bf16(wf, cb, (f32x4){0.f, 0.f, 0.f, 0.f});
                racc_update(racc, r0 + (size_t)mi * 32 + wm * 16 + lq * 4,
                            c0 + wn * 64 + nj * 16 + lr, d, initR);
            }
        }
    }
#undef AIDX
#undef BIDX
#undef STAGE
#undef PHASE
}

// ---------------------------------------------------------------------------
// gemm_fp8: MX-fp8 GEMM (256x256 tile, BK=128, 32 K-tiles, 2 phases/tile).
//   acc = TRUE values (HW scale-fold). Epilogue: optional Y fp8 store (*ysc)
//   + MFMA channel-mix into bf16 racc (scattered per-lane RMW).
__device__ __forceinline__ i32x8 ldfrag8(const uchar* lds8, int rbase, int row, int lq) {
    const int sw = (row & 7) << 4;
    const int b  = rbase + row * 128;
    i32x4 lo = *(const i32x4*)&lds8[b + ((lq * 32) ^ sw)];
    i32x4 hi = *(const i32x4*)&lds8[b + ((lq * 32 + 16) ^ sw)];
    return (i32x8){lo[0], lo[1], lo[2], lo[3], hi[0], hi[1], hi[2], hi[3]};
}

__global__ __launch_bounds__(512, 2)
void gemm_fp8(const uchar* __restrict__ Xp, const uchar* __restrict__ Bt,
              uchar* __restrict__ Yp, ushort* __restrict__ racc,
              const float* __restrict__ W, int cblk, int writeY, int initR,
              int sA, int sB, float ysc) {
    __shared__ uchar lds8[131072];   // 2 buf x (A 32KB + B 32KB)
    const int tid  = threadIdx.x;
    const int lane = tid & 63;
    const int wid  = tid >> 6;
    const int wm   = wid >> 2;
    const int wn   = wid & 3;
    const int lr   = lane & 15;
    const int lq   = lane >> 4;

    int flat = blockIdx.y * gridDim.x + blockIdx.x;   // grid (16,48)
    int swz  = (flat & 7) * 96 + (flat >> 3);
    const size_t r0 = (size_t)(swz >> 4) * 256;
    const size_t c0 = (size_t)(swz & 15) * 256;

#define STAGE8(P, rg0, tt, h, mat)                                                       \
    {                                                                                    \
        uchar* _base = &lds8[((tt) & 1) * 65536 + (mat) * 32768 + (h) * 16384];          \
        const size_t _k0 = (size_t)(tt) * 128;                                           \
        _Pragma("unroll")                                                                \
        for (int _i = 0; _i < 2; ++_i) {                                                 \
            int _e   = (_i * 512 + tid) * 16;                                            \
            int _row = _e >> 7;                                                          \
            int _col = (_e & 127) ^ ((_row & 7) << 4);                                   \
            gload16b(&(P)[((rg0) + (h) * 128 + _row) * 4096 + _k0 + _col], &_base[_e]);  \
        }                                                                                \
    }

    f32x4 acc[8][4] = {};

    STAGE8(Xp, r0, 0, 0, 0);
    STAGE8(Xp, r0, 0, 1, 0);
    STAGE8(Bt, c0, 0, 0, 1);
    STAGE8(Bt, c0, 0, 1, 1);
    STAGE8(Xp, r0, 1, 0, 0);
    STAGE8(Bt, c0, 1, 0, 1);
    asm volatile("s_waitcnt vmcnt(4)" ::: "memory");
    __builtin_amdgcn_s_barrier();

    for (int t = 0; t < 32; ++t) {
        const int bb = (t & 1) * 65536;
        i32x8 bf[4];
        // ===== phase 0: stage A1(t+1), B1(t+1); compute mi 0-3 =====
        if (t + 1 < 32) STAGE8(Xp, r0, t + 1, 1, 0);
        #pragma unroll
        for (int nj = 0; nj < 4; ++nj)
            bf[nj] = ldfrag8(lds8, bb + 32768, wn * 64 + nj * 16 + lr, lq);
        i32x8 af0 = ldfrag8(lds8, bb,       wm * 16 + lr, lq);
        i32x8 af1 = ldfrag8(lds8, bb,  32 + wm * 16 + lr, lq);
        i32x8 af2 = ldfrag8(lds8, bb,  64 + wm * 16 + lr, lq);
        i32x8 af3 = ldfrag8(lds8, bb,  96 + wm * 16 + lr, lq);
        if (t + 1 < 32) STAGE8(Bt, c0, t + 1, 1, 1);
        __builtin_amdgcn_s_barrier();
        __builtin_amdgcn_s_setprio(1);
        #pragma unroll
        for (int nj = 0; nj < 4; ++nj) {
            acc[0][nj] = __builtin_amdgcn_mfma_scale_f32_16x16x128_f8f6f4(af0, bf[nj], acc[0][nj], 0, 0, 0, sA, 0, sB);
            acc[1][nj] = __builtin_amdgcn_mfma_scale_f32_16x16x128_f8f6f4(af1, bf[nj], acc[1][nj], 0, 0, 0, sA, 0, sB);
            acc[2][nj] = __builtin_amdgcn_mfma_scale_f32_16x16x128_f8f6f4(af2, bf[nj], acc[2][nj], 0, 0, 0, sA, 0, sB);
            acc[3][nj] = __builtin_amdgcn_mfma_scale_f32_16x16x128_f8f6f4(af3, bf[nj], acc[3][nj], 0, 0, 0, sA, 0, sB);
        }
        __builtin_amdgcn_s_setprio(0);
        __builtin_amdgcn_s_barrier();
        // ===== phase 1: stage A0(t+2), B0(t+2); compute mi 4-7 =====
        if (t + 2 < 32) STAGE8(Xp, r0, t + 2, 0, 0);
        af0 = ldfrag8(lds8, bb, 128 + wm * 16 + lr, lq);
        af1 = ldfrag8(lds8, bb, 160 + wm * 16 + lr, lq);
        af2 = ldfrag8(lds8, bb, 192 + wm * 16 + lr, lq);
        af3 = ldfrag8(lds8, bb, 224 + wm * 16 + lr, lq);
        if (t + 2 < 32) STAGE8(Bt, c0, t + 2, 0, 1);
        __builtin_amdgcn_s_barrier();
        __builtin_amdgcn_s_setprio(1);
        #pragma unroll
        for (int nj = 0; nj < 4; ++nj) {
            acc[4][nj] = __builtin_amdgcn_mfma_scale_f32_16x16x128_f8f6f4(af0, bf[nj], acc[4][nj], 0, 0, 0, sA, 0, sB);
            acc[5][nj] = __builtin_amdgcn_mfma_scale_f32_16x16x128_f8f6f4(af1, bf[nj], acc[5][nj], 0, 0, 0, sA, 0, sB);
            acc[6][nj] = __builtin_amdgcn_mfma_scale_f32_16x16x128_f8f6f4(af2, bf[nj], acc[6][nj], 0, 0, 0, sA, 0, sB);
            acc[7][nj] = __builtin_amdgcn_mfma_scale_f32_16x16x128_f8f6f4(af3, bf[nj], acc[7][nj], 0, 0, 0, sA, 0, sB);
        }
        __builtin_amdgcn_s_setprio(0);
        if (t < 30)       { asm volatile("s_waitcnt vmcnt(4)" ::: "memory"); }
        else if (t == 30) { asm volatile("s_waitcnt vmcnt(0)" ::: "memory"); }
        __builtin_amdgcn_sched_barrier(0);
        __builtin_amdgcn_s_barrier();
    }

    // epilogue 1: Y fp8 store (value * ysc), LDS restage for coalescing
    if (writeY) {
        #pragma unroll
        for (int mi = 0; mi < 8; ++mi) {
            #pragma unroll
            for (int nj = 0; nj < 4; ++nj) {
                const int col = wn * 64 + nj * 16 + lr;
                #pragma unroll
                for (int r = 0; r < 4; ++r) {
                    const int rr = mi * 32 + wm * 16 + lq * 4 + r;
                    lds8[(rr * 256 + col) ^ ((rr & 7) << 4)] = f2fp8(acc[mi][nj][r] * ysc);
                }
            }
        }
        __syncthreads();
        #pragma unroll
        for (int it = 0; it < 8; ++it) {
            int e = it * 8192 + tid * 16;
            int row = e >> 8, colu = e & 255;
            i32x4 v = *(const i32x4*)&lds8[e ^ ((row & 7) << 4)];
            *(i32x4*)&Yp[(r0 + row) * 4096 + c0 + colu] = v;
        }
    }

    // epilogue 2: MFMA channel-mix into bf16 racc (scattered per-lane RMW)
    {
        const float4 wv4 = *(const float4*)&W[(size_t)lr * 112 + cblk + lq * 4];
        s16x4 wf;
        wf[0] = (short)f2bf(wv4.x); wf[1] = (short)f2bf(wv4.y);
        wf[2] = (short)f2bf(wv4.z); wf[3] = (short)f2bf(wv4.w);
        #pragma unroll
        for (int mi = 0; mi < 8; ++mi) {
            #pragma unroll
            for (int nj = 0; nj < 4; ++nj) {
                s16x4 cb;
                cb[0] = (short)f2bf(acc[mi][nj][0]); cb[1] = (short)f2bf(acc[mi][nj][1]);
                cb[2] = (short)f2bf(acc[mi][nj][2]); cb[3] = (short)f2bf(acc[mi][nj][3]);
                f32x4 d = mfma16x16x16bf16(wf, cb, (f32x4){0.f, 0.f, 0.f, 0.f});
                racc_update(racc, r0 + (size_t)mi * 32 + wm * 16 + lq * 4,
                            c0 + wn * 64 + nj * 16 + lr, d, initR);
            }
        }
    }
#undef STAGE8
}

// ---------------------------------------------------------------------------
// final_out: out[b,c,n,t] = x + bias[c] + W0-mix(x) + racc[(b*12+t)*16+c][n]
// x taken from X2 (bf16). grid (N/32, B), block 256
__global__ __launch_bounds__(256)
void final_out(const ushort* __restrict__ racc, const ushort* __restrict__ X2,
               const float* __restrict__ W, const float* __restrict__ bias,
               float* __restrict__ out) {
    __shared__ float fr[192][32];
    __shared__ float xsb[192][32];
    __shared__ float sW[16][16];
    __shared__ float sb[16];
    const int t  = threadIdx.x;
    const int n0 = blockIdx.x * 32;
    const int b  = blockIdx.y;
    sW[t >> 4][t & 15] = W[(t >> 4) * 112 + (t & 15)];
    if (t < 16) sb[t] = bias[t];
    #pragma unroll
    for (int i = 0; i < 24; ++i) {
        int e = i * 256 + t;
        int rr = e >> 5, nn = e & 31;
        size_t off = ((size_t)b * 192 + rr) * 4096 + n0 + nn;
        fr[rr][nn]  = bf2f(racc[off]);
        xsb[rr][nn] = bf2f(X2[off]);
    }
    __syncthreads();
    #pragma unroll
    for (int p0 = 0; p0 < 2; ++p0) {
        int p = p0 * 256 + t;
        int c = p >> 5, nn = p & 31;
        float buf[12];
        #pragma unroll
        for (int tt = 0; tt < 12; ++tt) {
            float acc = xsb[tt * 16 + c][nn] + sb[c] + fr[tt * 16 + c][nn];
            #pragma unroll
            for (int cp = 0; cp < 16; ++cp) acc += sW[c][cp] * xsb[tt * 16 + cp][nn];
            buf[tt] = acc;
        }
        float* dst = &out[(size_t)((b * 16 + c) * 4096 + n0 + nn) * 12];
        *(float4*)(dst)     = *(float4*)(buf);
        *(float4*)(dst + 4) = *(float4*)(buf + 4);
        *(float4*)(dst + 8) = *(float4*)(buf + 8);
    }
}

// ---------------------------------------------------------------------------
extern "C" void kernel_launch(void* const* d_in, const int* in_sizes, int n_in,
                              void* d_out, int out_size, void* d_ws, size_t ws_size,
                              hipStream_t stream) {
    const float* x    = (const float*)d_in[0];
    const float* s0   = (const float*)d_in[1];
    const float* s1   = (const float*)d_in[2];
    const float* e1   = (const float*)d_in[3];
    const float* e2   = (const float*)d_in[4];
    const float* W    = (const float*)d_in[5];
    const float* bias = (const float*)d_in[6];
    float* out = (float*)d_out;

    // Workspace layout (~403 MB):
    //  X2 bf16 100.66 | racc bf16 100.66 | REGA 100.66 (Y80+Y81 fp8 -> Y1adp bf16)
    //  | X8 fp8 50.33 | SF fp8 16.78 | ADT bf16 33.55 | maxn/sumn 32KB
    char* ws = (char*)d_ws;
    const size_t SZ_X2 = (size_t)ROWS_ * 4096 * 2;
    const size_t SZ_X8 = (size_t)ROWS_ * 4096;
    const size_t SZ_SF = (size_t)4096 * 4096;

    ushort* X2   = (ushort*)(ws);
    ushort* racc = (ushort*)(ws + SZ_X2);
    char*   REGA = ws + 2 * SZ_X2;
    uchar*  X8   = (uchar*)(REGA + SZ_X2);
    uchar*  SF   = (uchar*)((char*)X8 + SZ_X8);
    ushort* ADT  = (ushort*)((char*)SF + SZ_SF);
    float*  maxn = (float*)((char*)ADT + SZ_SF * 2);
    float*  sumn = maxn + 4096;

    uchar*  Y80   = (uchar*)REGA;              // s0 chain Y1 (fp8 * 2^6)
    uchar*  Y81   = (uchar*)REGA + SZ_X8;      // s1 chain Y1
    ushort* Y1adp = (ushort*)REGA;             // adp chain Y1 (bf16), after Y8 dead

    const int S_ONE = 0x7F7F7F7F;   // E8M0 2^0
    const int S_M6  = 0x79797979;   // 2^-6  (s-chain Y stored *2^6)
    const int S_M12 = 0x73737373;   // 2^-12 (supports stored *2^12)

    pack_x<<<dim3(128, 64), 256, 0, stream>>>(x, X2, X8);
    transpose_fp8<<<dim3(64, 64), 256, 0, stream>>>(s0, SF, 4096.f);
    adp_rows<<<4096, 256, 0, stream>>>(e1, e2, maxn, sumn);
    adp_make<<<dim3(64, 64), 256, 0, stream>>>(e1, e2, maxn, sumn, ADT);

    // s0 chain (fp8) — first GEMM initializes racc (store, no read)
    gemm_fp8<<<dim3(16, 48), 512, 0, stream>>>(X8,  SF, Y80, racc, W, 16, 1, 1, S_ONE, S_M12, 64.f);
    gemm_fp8<<<dim3(16, 48), 512, 0, stream>>>(Y80, SF, Y80, racc, W, 32, 0, 0, S_M6,  S_M12, 0.f);
    // s1 chain (fp8) — SF reused after s0 chain finished
    transpose_fp8<<<dim3(64, 64), 256, 0, stream>>>(s1, SF, 4096.f);
    gemm_fp8<<<dim3(16, 48), 512, 0, stream>>>(X8,  SF, Y81, racc, W, 48, 1, 0, S_ONE, S_M12, 64.f);
    gemm_fp8<<<dim3(16, 48), 512, 0, stream>>>(Y81, SF, Y81, racc, W, 64, 0, 0, S_M6,  S_M12, 0.f);
    // adp chain (bf16) — Y1adp overwrites dead Y80/Y81
    gemm_mix<<<dim3(16, 48), 512, 0, stream>>>(X2,    ADT, Y1adp, racc, W, 80, 1, 0);
    gemm_mix<<<dim3(16, 48), 512, 0, stream>>>(Y1adp, ADT, Y1adp, racc, W, 96, 0, 0);

    final_out<<<dim3(128, 64), 256, 0, stream>>>(racc, X2, W, bias, out);
}